// Round 17
// baseline (170.725 us; speedup 1.0000x reference)
//
#include <hip/hip_runtime.h>
#include <hip/hip_bf16.h>
#include <math.h>

typedef _Float16 f16x8 __attribute__((ext_vector_type(8)));
typedef float f32x4 __attribute__((ext_vector_type(4)));

#define N_TOK 16384
#define D 256
#define K 8192

#define Q_OFF 0
#define IND_OFF 4194304
#define PERP_OFF 4210688
#define COMMIT_OFF 4210689

// ---------- ws layout (bytes) ----------
#define WS_CAND   0u          // u32[16384][16]  (1 MB)
#define WS_E2     1048576u    // f32[8192]
#define WS_DSUM   1081344u    // double
#define WS_EH     1114112u    // f16 tiled ehT[512 tiles][32 chunks][16 rows][8] (4 MB)
#define WS_XH     5308416u    // f16[16384][256] (8 MB)
#define WS_XT     13697024u   // f32[16384][256] (16 MB)
#define WS_NEED   30474240u

__device__ __forceinline__ unsigned int ford(float f) {
    unsigned int u = __float_as_uint(f);
    return (u & 0x80000000u) ? ~u : (u | 0x80000000u);
}
__device__ __forceinline__ unsigned short f2h(float f) {
    _Float16 h = (_Float16)f;
    return *(unsigned short*)&h;
}

// ============================ FAST PATH ============================

// transpose x: (b,c,p) f32 -> XT[n][c] f32 and Xh[n][c] f16 (row-major)
__global__ void vq_convert_x(const float* __restrict__ x, float* __restrict__ xt,
                             unsigned short* __restrict__ xh) {
    __shared__ float t[64][65];
    const int tid = threadIdx.x;
    const int p0 = blockIdx.x * 64, c0 = blockIdx.y * 64, b = blockIdx.z;
    const int q = tid & 15, h = tid >> 4;
    #pragma unroll
    for (int r = 0; r < 4; ++r) {
        const int cl = r * 16 + h;
        const float4 v = *(const float4*)(x + (((size_t)(b * 256 + c0 + cl)) << 10) + p0 + q * 4);
        t[cl][q * 4 + 0] = v.x; t[cl][q * 4 + 1] = v.y;
        t[cl][q * 4 + 2] = v.z; t[cl][q * 4 + 3] = v.w;
    }
    __syncthreads();
    #pragma unroll
    for (int r = 0; r < 4; ++r) {
        const int nl = r * 16 + h;
        const int n = (b << 10) + p0 + nl;
        const int c = c0 + q * 4;
        float4 vf; ushort4 vh;
        vf.x = t[q * 4 + 0][nl]; vf.y = t[q * 4 + 1][nl];
        vf.z = t[q * 4 + 2][nl]; vf.w = t[q * 4 + 3][nl];
        vh.x = f2h(vf.x); vh.y = f2h(vf.y); vh.z = f2h(vf.z); vh.w = f2h(vf.w);
        *(float4*)(xt + ((size_t)n << 8) + c) = vf;
        *(ushort4*)(xh + ((size_t)n << 8) + c) = vh;
    }
}

// fused: embed -> f16 in MFMA-fragment tiled order, e2 row norms, dsum init.
// ehT element index = (c>>4)*4096 + (k>>3)*128 + (c&15)*8 + (k&7).
__global__ void vq_prep_e(const float* __restrict__ e, unsigned short* __restrict__ ehT,
                          float* __restrict__ e2, double* __restrict__ dsum) {
    if (blockIdx.x == 0 && threadIdx.x == 0) *dsum = 0.0;
    const int wave = threadIdx.x >> 6, lane = threadIdx.x & 63;
    const int c = blockIdx.x * 4 + wave;
    const float4 v = *(const float4*)(e + (size_t)c * D + lane * 4);
    ushort4 vh;
    vh.x = f2h(v.x); vh.y = f2h(v.y); vh.z = f2h(v.z); vh.w = f2h(v.w);
    unsigned short* dst = ehT + (((size_t)(c >> 4)) << 12) + ((lane >> 1) << 7) +
                          ((c & 15) << 3) + ((lane & 1) << 2);
    *(ushort4*)dst = vh;
    float s = v.x * v.x + v.y * v.y + v.z * v.z + v.w * v.w;
    #pragma unroll
    for (int off = 32; off > 0; off >>= 1) s += __shfl_down(s, off, 64);
    if (lane == 0) e2[c] = s;
}

// fp16 screen GEMM + per-split top-2 -- zero LDS staging, software-pipelined
// (b(t+1) loads before MFMA(t), EPI(t-1) in MFMA shadow), 32 rows/wave,
// ~3 waves/SIMD TLP. NEW vs r16: (1) raw s_barrier per outer iter keeps the
// block's 4 waves lockstep so their identical B streams alias in L1 (cuts L2
// traffic ~4x); (2) 1D grid with split = wg&7 -> XCD-affine splits (each
// XCD's L2 permanently holds its split's 512KB panel).
// grid 1024 blocks x 256 threads (4 waves x 32 rows).
__global__ __launch_bounds__(256)
void vq_mfma_kernel(
    const unsigned short* __restrict__ xh, const unsigned short* __restrict__ ehT,
    const float* __restrict__ e2, unsigned int* __restrict__ cand) {
    __shared__ float e2s[1024];  // 4 KB, pre-biased +512

    const int tid = threadIdx.x;
    const int lane = tid & 63, wid = tid >> 6;   // 4 waves
    const int l15 = lane & 15, lg = lane >> 4;
    const int wg = blockIdx.x;
    const int split = wg & 7;          // XCD-affine under round-robin dispatch
    const int m0 = (wg >> 3) * 128;
    const int c0s = split * 1024;
    const int rw = m0 + wid * 32;  // wave's first token row (32 rows/wave)

    {
        float4 v = *(const float4*)(e2 + c0s + tid * 4);
        v.x += 512.0f; v.y += 512.0f; v.z += 512.0f; v.w += 512.0f;
        *(float4*)&e2s[tid * 4] = v;
    }

    // ---- A fragments: 32 rows x 256 K per wave (one-time load) ----
    f16x8 a[2][8];
    #pragma unroll
    for (int mf = 0; mf < 2; ++mf) {
        const unsigned short* ap = xh + (((size_t)(rw + mf * 16 + l15)) << 8) + lg * 8;
        #pragma unroll
        for (int t = 0; t < 8; ++t)
            a[mf][t] = *(const f16x8*)(ap + t * 32);
    }
    __syncthreads();  // e2s visible

    // per-lane B base for this split (tiled layout): + tile*8192 + j*1024
    const char* bb = (const char*)ehT + (((size_t)c0s) << 9) + lane * 16;

    unsigned int p1[8], p2[8];
    #pragma unroll
    for (int r = 0; r < 8; ++r) { p1[r] = 0xFFFFFFFFu; p2[r] = 0xFFFFFFFFu; }

    f16x8 bA[8], bB[8];
    f32x4 accA[2], accB[2];

#define LOADT(breg, t)                                            \
    {                                                             \
        const char* tb_ = bb + (t) * 8192;                        \
        _Pragma("unroll")                                         \
        for (int j_ = 0; j_ < 8; ++j_)                            \
            breg[j_] = *(const f16x8*)(tb_ + j_ * 1024);          \
    }

#define MFMAT(acc, breg)                                          \
    {                                                             \
        _Pragma("unroll")                                         \
        for (int mf_ = 0; mf_ < 2; ++mf_) {                       \
            f32x4 z_ = {0.f, 0.f, 0.f, 0.f};                      \
            acc[mf_] = z_;                                        \
        }                                                         \
        _Pragma("unroll")                                         \
        for (int j_ = 0; j_ < 8; ++j_)                            \
            _Pragma("unroll")                                     \
            for (int mf_ = 0; mf_ < 2; ++mf_)                     \
                acc[mf_] = __builtin_amdgcn_mfma_f32_16x16x32_f16(\
                    a[mf_][j_], breg[j_], acc[mf_], 0, 0, 0);     \
    }

// biased-positive scores: raw bits are order-preserving; pack idx in low 10.
#define EPI(acc, tile)                                                        \
    {                                                                         \
        const float e2v_ = e2s[(tile) * 16 + l15];                            \
        const unsigned int cl_ = (unsigned int)((tile) * 16 + l15);           \
        _Pragma("unroll")                                                     \
        for (int mf_ = 0; mf_ < 2; ++mf_)                                     \
            _Pragma("unroll")                                                 \
            for (int rg_ = 0; rg_ < 4; ++rg_) {                               \
                const int rr_ = mf_ * 4 + rg_;                                \
                const float s_ = fmaf(-2.0f, acc[mf_][rg_], e2v_);            \
                const unsigned int sp_ =                                      \
                    (__float_as_uint(s_) & 0xFFFFFC00u) | cl_;                \
                const unsigned int hi_ = p1[rr_] > sp_ ? p1[rr_] : sp_;       \
                p1[rr_] = p1[rr_] < sp_ ? p1[rr_] : sp_;                      \
                p2[rr_] = p2[rr_] < hi_ ? p2[rr_] : hi_;                      \
            }                                                                 \
    }

    LOADT(bA, 0);
    #pragma unroll 1
    for (int t = 0; t < 64; t += 2) {
        __builtin_amdgcn_s_barrier();  // lockstep waves -> B streams alias in L1
        LOADT(bB, t + 1);          // t+1 <= 63 always
        MFMAT(accA, bA);
        if (t > 0) EPI(accB, t - 1);
        if (t + 2 < 64) LOADT(bA, t + 2);
        MFMAT(accB, bB);
        EPI(accA, t);
    }
    EPI(accB, 63);

    // butterfly top-2 merge across the 16-lane group (u32 packed)
    #pragma unroll
    for (int st = 1; st < 16; st <<= 1) {
        #pragma unroll
        for (int r = 0; r < 8; ++r) {
            const unsigned int q1 = (unsigned int)__shfl_xor((int)p1[r], st, 64);
            const unsigned int q2 = (unsigned int)__shfl_xor((int)p2[r], st, 64);
            const unsigned int n1 = p1[r] < q1 ? p1[r] : q1;
            const unsigned int hi = p1[r] < q1 ? q1 : p1[r];
            const unsigned int m2 = p2[r] < q2 ? p2[r] : q2;
            p1[r] = n1;
            p2[r] = m2 < hi ? m2 : hi;
        }
    }
    // waves own disjoint rows -> direct global write (code = c0s + idx10)
    if (l15 == 0) {
        #pragma unroll
        for (int mf = 0; mf < 2; ++mf)
            #pragma unroll
            for (int reg = 0; reg < 4; ++reg) {
                const int rr = mf * 4 + reg;
                const int n = rw + mf * 16 + lg * 4 + reg;
                unsigned int* cp = cand + (((size_t)n) << 4) + split * 2;
                cp[0] = (unsigned int)(c0s + (p1[rr] & 0x3FFu));
                cp[1] = (unsigned int)(c0s + (p2[rr] & 0x3FFu));
            }
    }
#undef LOADT
#undef MFMAT
#undef EPI
}

// exact f32 rescore of 16 candidates + gather + commit loss, fused.
// grid 512 blocks x 256 threads; 32 tokens/block (8 iters x 4 waves).
__global__ void vq_rescore_finalize(const float* __restrict__ xt, const float* __restrict__ embed,
                                    const float* __restrict__ e2,
                                    const unsigned int* __restrict__ cand,
                                    float* __restrict__ out, double* __restrict__ dsum) {
    __shared__ double red[4];
    const int tid = threadIdx.x, wid = tid >> 6, lane = tid & 63;
    double wsum = 0.0;
    #pragma unroll 1
    for (int it = 0; it < 8; ++it) {
        const int n = blockIdx.x * 32 + it * 4 + wid;
        const float4 xv = *(const float4*)(xt + (((size_t)n) << 8) + lane * 4);
        unsigned long long best = 0xFFFFFFFFFFFFFFFFull;
        #pragma unroll 2
        for (int j = 0; j < 16; ++j) {
            const unsigned int c = cand[(((size_t)n) << 4) + j];
            const float4 ev = *(const float4*)(embed + (((size_t)c) << 8) + lane * 4);
            float dt = xv.x * ev.x + xv.y * ev.y + xv.z * ev.z + xv.w * ev.w;
            #pragma unroll
            for (int off = 32; off > 0; off >>= 1) dt += __shfl_xor(dt, off, 64);
            const float s = fmaf(-2.0f, dt, e2[c]);
            const unsigned long long p = (((unsigned long long)ford(s)) << 32) | c;
            best = p < best ? p : best;
        }
        const unsigned int bi = (unsigned int)(best & 0xFFFFFFFFull);
        if (lane == 0) out[IND_OFF + n] = (float)bi;
        const float4 ev = *(const float4*)(embed + (((size_t)bi) << 8) + lane * 4);
        *(float4*)(out + Q_OFF + (((size_t)n) << 8) + lane * 4) = ev;
        const float q0 = ev.x - xv.x, q1 = ev.y - xv.y, q2 = ev.z - xv.z, q3 = ev.w - xv.w;
        float a4 = q0 * q0 + q1 * q1 + q2 * q2 + q3 * q3;
        #pragma unroll
        for (int off = 32; off > 0; off >>= 1) a4 += __shfl_xor(a4, off, 64);
        if (lane == 0) wsum += (double)a4;
    }
    if (lane == 0) red[wid] = wsum;
    __syncthreads();
    if (tid == 0) atomicAdd(dsum, red[0] + red[1] + red[2] + red[3]);
}

__global__ void vq_tail_kernel(const float* __restrict__ cs,
                               const double* __restrict__ dsum,
                               float* __restrict__ out) {
    __shared__ double red[4];
    const int tid = threadIdx.x;
    double s = 0.0;
    for (int i = tid; i < K; i += 256) {
        const float p = cs[i];
        s += (double)(p * logf(p + 1e-5f));
    }
    #pragma unroll
    for (int off = 32; off > 0; off >>= 1) s += __shfl_down(s, off, 64);
    if ((tid & 63) == 0) red[tid >> 6] = s;
    __syncthreads();
    if (tid == 0) {
        const double tot = red[0] + red[1] + red[2] + red[3];
        const double pv = exp(-tot);
        out[PERP_OFF] = (pv > 3.3e38) ? 3.3e38f : (float)pv;
        out[COMMIT_OFF] = (float)(*dsum * (1.0 / 4194304.0));
    }
}

// ============================ FALLBACK (ws too small) ============================
#define TM 64
#define TN 64
#define BKF 32
#define NSPLITF 2
#define CODES_PER_SPLIT (K / NSPLITF)
#define TILES_PER_SPLIT (CODES_PER_SPLIT / TN)

__global__ void vq_init_kernel(unsigned long long* __restrict__ keys, double* __restrict__ dsum) {
    int i = blockIdx.x * blockDim.x + threadIdx.x;
    if (i < N_TOK) keys[i] = 0xFFFFFFFFFFFFFFFFull;
    if (i == 0) *dsum = 0.0;
}
__global__ void vq_e2_kernel(const float* __restrict__ embed, float* __restrict__ e2) {
    int wave = threadIdx.x >> 6, lane = threadIdx.x & 63;
    int c = blockIdx.x * 4 + wave;
    const float4 v = *(const float4*)(embed + (size_t)c * D + lane * 4);
    float s = v.x * v.x + v.y * v.y + v.z * v.z + v.w * v.w;
    #pragma unroll
    for (int off = 32; off > 0; off >>= 1) s += __shfl_down(s, off, 64);
    if (lane == 0) e2[c] = s;
}
__global__ __launch_bounds__(256, 2) void vq_argmin_kernel(
    const float* __restrict__ x, const float* __restrict__ embed,
    const float* __restrict__ e2, unsigned long long* __restrict__ keys) {
    __shared__ float xT[D][TM];
    __shared__ float eT[BKF][TN + 4];
    const int tid = threadIdx.x;
    const int n0 = blockIdx.x * TM;
    const int b = n0 >> 10, p0 = n0 & 1023;
    const float* xb = x + (size_t)b * D * 1024 + p0;
    {
        const int t4 = (tid & 15) * 4, chb = tid >> 4;
        #pragma unroll
        for (int pass = 0; pass < 16; ++pass) {
            const int ch = pass * 16 + chb;
            *(float4*)&xT[ch][t4] = *(const float4*)(xb + (size_t)ch * 1024 + t4);
        }
    }
    __syncthreads();
    const int tm4 = (tid & 15) * 4, tn = tid >> 4, tn4 = tn * 4;
    float bestd[4]; int besti[4];
    #pragma unroll
    for (int i = 0; i < 4; ++i) { bestd[i] = INFINITY; besti[i] = 0x7fffffff; }
    for (int ct = 0; ct < TILES_PER_SPLIT; ++ct) {
        const int c0 = blockIdx.y * CODES_PER_SPLIT + ct * TN;
        float acc[4][4] = {};
        for (int kk = 0; kk < D; kk += BKF) {
            {
                const int j = tid >> 2, ch4 = (tid & 3) * 4;
                #pragma unroll
                for (int p = 0; p < 2; ++p) {
                    const int chl = p * 16 + ch4;
                    const float4 ev = *(const float4*)(embed + (size_t)(c0 + j) * D + kk + chl);
                    eT[chl + 0][j] = ev.x; eT[chl + 1][j] = ev.y;
                    eT[chl + 2][j] = ev.z; eT[chl + 3][j] = ev.w;
                }
            }
            __syncthreads();
            #pragma unroll
            for (int k2 = 0; k2 < BKF; ++k2) {
                const float4 a = *(const float4*)&xT[kk + k2][tm4];
                const float4 bv = *(const float4*)&eT[k2][tn4];
                acc[0][0] += a.x * bv.x; acc[0][1] += a.x * bv.y; acc[0][2] += a.x * bv.z; acc[0][3] += a.x * bv.w;
                acc[1][0] += a.y * bv.x; acc[1][1] += a.y * bv.y; acc[1][2] += a.y * bv.z; acc[1][3] += a.y * bv.w;
                acc[2][0] += a.z * bv.x; acc[2][1] += a.z * bv.y; acc[2][2] += a.z * bv.z; acc[2][3] += a.z * bv.w;
                acc[3][0] += a.w * bv.x; acc[3][1] += a.w * bv.y; acc[3][2] += a.w * bv.z; acc[3][3] += a.w * bv.w;
            }
            __syncthreads();
        }
        #pragma unroll
        for (int j = 0; j < 4; ++j) {
            const int c = c0 + tn4 + j;
            const float ec = e2[c];
            #pragma unroll
            for (int i = 0; i < 4; ++i) {
                const float s = ec - 2.0f * acc[i][j];
                if (s < bestd[i]) { bestd[i] = s; besti[i] = c; }
            }
        }
    }
    __syncthreads();
    float* cd = &eT[0][0];
    int* ci = (int*)&eT[16][0];
    #pragma unroll
    for (int i = 0; i < 4; ++i) { cd[tn * 64 + tm4 + i] = bestd[i]; ci[tn * 64 + tm4 + i] = besti[i]; }
    __syncthreads();
    if (tid < TM) {
        float bd = INFINITY; int bi = 0x7fffffff;
        for (int j = 0; j < 16; ++j) {
            const float d = cd[j * 64 + tid]; const int idx = ci[j * 64 + tid];
            if (d < bd || (d == bd && idx < bi)) { bd = d; bi = idx; }
        }
        atomicMin(&keys[n0 + tid], (((unsigned long long)ford(bd)) << 32) | (unsigned int)bi);
    }
}
__global__ void vq_finalize_kernel(const float* __restrict__ x, const float* __restrict__ embed,
                                   const unsigned long long* __restrict__ keys,
                                   float* __restrict__ out, double* __restrict__ dsum) {
    const int tid = threadIdx.x;
    const int n0 = blockIdx.x * 64;
    const int t = tid >> 2, q = tid & 3;
    const int n = n0 + t;
    const int b = n >> 10, p = n & 1023;
    if (tid < 64) {
        const int nn = n0 + tid;
        out[IND_OFF + nn] = (float)(int)(unsigned int)(keys[nn] & 0xFFFFFFFFull);
    }
    const int idx = (int)(unsigned int)(keys[n] & 0xFFFFFFFFull);
    const float* erow = embed + (size_t)idx * D;
    const float* xrow = x + (size_t)b * D * 1024 + p;
    float* qrow = out + Q_OFF + (size_t)n * D;
    float acc = 0.0f;
    #pragma unroll
    for (int i = 0; i < 16; ++i) {
        const int ch = i * 16 + q * 4;
        const float4 ev = *(const float4*)(erow + ch);
        *(float4*)(qrow + ch) = ev;
        const float x0 = xrow[(size_t)(ch + 0) * 1024];
        const float x1 = xrow[(size_t)(ch + 1) * 1024];
        const float x2 = xrow[(size_t)(ch + 2) * 1024];
        const float x3 = xrow[(size_t)(ch + 3) * 1024];
        const float d0 = ev.x - x0, d1 = ev.y - x1, d2 = ev.z - x2, d3 = ev.w - x3;
        acc += d0 * d0 + d1 * d1 + d2 * d2 + d3 * d3;
    }
    #pragma unroll
    for (int off = 32; off > 0; off >>= 1) acc += __shfl_down(acc, off, 64);
    if ((tid & 63) == 0) atomicAdd(dsum, (double)acc);
}

extern "C" void kernel_launch(void* const* d_in, const int* in_sizes, int n_in,
                              void* d_out, int out_size, void* d_ws, size_t ws_size,
                              hipStream_t stream) {
    const float* x = (const float*)d_in[0];
    const float* embed = (const float*)d_in[1];
    const float* cs = (const float*)d_in[2];
    float* out = (float*)d_out;
    char* ws = (char*)d_ws;

    if (ws_size >= (size_t)WS_NEED) {
        unsigned int* cand = (unsigned int*)(ws + WS_CAND);
        float* e2 = (float*)(ws + WS_E2);
        double* dsum = (double*)(ws + WS_DSUM);
        unsigned short* ehT = (unsigned short*)(ws + WS_EH);
        unsigned short* xh = (unsigned short*)(ws + WS_XH);
        float* xt = (float*)(ws + WS_XT);

        vq_prep_e<<<dim3(K / 4), dim3(256), 0, stream>>>(embed, ehT, e2, dsum);
        vq_convert_x<<<dim3(16, 4, 16), dim3(256), 0, stream>>>(x, xt, xh);
        vq_mfma_kernel<<<dim3(1024), dim3(256), 0, stream>>>(xh, ehT, e2, cand);
        vq_rescore_finalize<<<dim3(512), dim3(256), 0, stream>>>(xt, embed, e2, cand, out, dsum);
        vq_tail_kernel<<<dim3(1), dim3(256), 0, stream>>>(cs, dsum, out);
    } else {
        unsigned long long* keys = (unsigned long long*)ws;
        float* e2 = (float*)(ws + 131072);
        double* dsum = (double*)(ws + 163840);
        vq_init_kernel<<<dim3(64), dim3(256), 0, stream>>>(keys, dsum);
        vq_e2_kernel<<<dim3(K / 4), dim3(256), 0, stream>>>(embed, e2);
        vq_argmin_kernel<<<dim3(N_TOK / TM, NSPLITF), dim3(256), 0, stream>>>(x, embed, e2, keys);
        vq_finalize_kernel<<<dim3(256), dim3(256), 0, stream>>>(x, embed, keys, out, dsum);
        vq_tail_kernel<<<dim3(1), dim3(256), 0, stream>>>(cs, dsum, out);
    }
}

// Round 18
// 159.983 us; speedup vs baseline: 1.0671x; 1.0671x over previous
//
#include <hip/hip_runtime.h>
#include <hip/hip_bf16.h>
#include <math.h>

typedef _Float16 f16x8 __attribute__((ext_vector_type(8)));
typedef float f32x4 __attribute__((ext_vector_type(4)));

#define N_TOK 16384
#define D 256
#define K 8192

#define Q_OFF 0
#define IND_OFF 4194304
#define PERP_OFF 4210688
#define COMMIT_OFF 4210689

// ---------- ws layout (bytes) ----------
#define WS_CAND   0u          // u32[16384][16]  (1 MB)
#define WS_E2     1048576u    // f32[8192]
#define WS_DSUM   1081344u    // double
#define WS_EH     1114112u    // f16 tiled ehT[512 tiles][32 chunks][16 rows][8] (4 MB)
#define WS_XH     5308416u    // f16[16384][256] (8 MB)
#define WS_XT     13697024u   // f32[16384][256] (16 MB)
#define WS_NEED   30474240u

__device__ __forceinline__ unsigned int ford(float f) {
    unsigned int u = __float_as_uint(f);
    return (u & 0x80000000u) ? ~u : (u | 0x80000000u);
}
__device__ __forceinline__ unsigned short f2h(float f) {
    _Float16 h = (_Float16)f;
    return *(unsigned short*)&h;
}

// ============================ FAST PATH ============================

// transpose x: (b,c,p) f32 -> XT[n][c] f32 and Xh[n][c] f16 (row-major)
__global__ void vq_convert_x(const float* __restrict__ x, float* __restrict__ xt,
                             unsigned short* __restrict__ xh) {
    __shared__ float t[64][65];
    const int tid = threadIdx.x;
    const int p0 = blockIdx.x * 64, c0 = blockIdx.y * 64, b = blockIdx.z;
    const int q = tid & 15, h = tid >> 4;
    #pragma unroll
    for (int r = 0; r < 4; ++r) {
        const int cl = r * 16 + h;
        const float4 v = *(const float4*)(x + (((size_t)(b * 256 + c0 + cl)) << 10) + p0 + q * 4);
        t[cl][q * 4 + 0] = v.x; t[cl][q * 4 + 1] = v.y;
        t[cl][q * 4 + 2] = v.z; t[cl][q * 4 + 3] = v.w;
    }
    __syncthreads();
    #pragma unroll
    for (int r = 0; r < 4; ++r) {
        const int nl = r * 16 + h;
        const int n = (b << 10) + p0 + nl;
        const int c = c0 + q * 4;
        float4 vf; ushort4 vh;
        vf.x = t[q * 4 + 0][nl]; vf.y = t[q * 4 + 1][nl];
        vf.z = t[q * 4 + 2][nl]; vf.w = t[q * 4 + 3][nl];
        vh.x = f2h(vf.x); vh.y = f2h(vf.y); vh.z = f2h(vf.z); vh.w = f2h(vf.w);
        *(float4*)(xt + ((size_t)n << 8) + c) = vf;
        *(ushort4*)(xh + ((size_t)n << 8) + c) = vh;
    }
}

// fused: embed -> f16 in MFMA-fragment tiled order, e2 row norms, dsum init.
// ehT element index = (c>>4)*4096 + (k>>3)*128 + (c&15)*8 + (k&7).
__global__ void vq_prep_e(const float* __restrict__ e, unsigned short* __restrict__ ehT,
                          float* __restrict__ e2, double* __restrict__ dsum) {
    if (blockIdx.x == 0 && threadIdx.x == 0) *dsum = 0.0;
    const int wave = threadIdx.x >> 6, lane = threadIdx.x & 63;
    const int c = blockIdx.x * 4 + wave;
    const float4 v = *(const float4*)(e + (size_t)c * D + lane * 4);
    ushort4 vh;
    vh.x = f2h(v.x); vh.y = f2h(v.y); vh.z = f2h(v.z); vh.w = f2h(v.w);
    unsigned short* dst = ehT + (((size_t)(c >> 4)) << 12) + ((lane >> 1) << 7) +
                          ((c & 15) << 3) + ((lane & 1) << 2);
    *(ushort4*)dst = vh;
    float s = v.x * v.x + v.y * v.y + v.z * v.z + v.w * v.w;
    #pragma unroll
    for (int off = 32; off > 0; off >>= 1) s += __shfl_down(s, off, 64);
    if (lane == 0) e2[c] = s;
}

// fp16 screen GEMM + per-split top-2 -- zero LDS staging, software-pipelined
// (b(t+1) loads before MFMA(t), EPI(t-1) in MFMA shadow), 32 rows/wave,
// ~3 waves/SIMD TLP. r18 = r16 + ONE change: raw s_barrier per outer iter
// keeps the block's 4 waves lockstep so their identical B streams alias in
// the per-CU L1 (expect ~4x L2-traffic cut). 2D grid kept (same-split blocks
// adjacent -> XCD L2 affinity preserved; r17's remap regressed FETCH).
// grid (128 M-tiles, 8 splits) = 1024 blocks of 256 threads (4 waves x 32 rows).
__global__ __launch_bounds__(256)
void vq_mfma_kernel(
    const unsigned short* __restrict__ xh, const unsigned short* __restrict__ ehT,
    const float* __restrict__ e2, unsigned int* __restrict__ cand) {
    __shared__ float e2s[1024];  // 4 KB, pre-biased +512

    const int tid = threadIdx.x;
    const int lane = tid & 63, wid = tid >> 6;   // 4 waves
    const int l15 = lane & 15, lg = lane >> 4;
    const int split = blockIdx.y;
    const int m0 = blockIdx.x * 128;
    const int c0s = split * 1024;
    const int rw = m0 + wid * 32;  // wave's first token row (32 rows/wave)

    {
        float4 v = *(const float4*)(e2 + c0s + tid * 4);
        v.x += 512.0f; v.y += 512.0f; v.z += 512.0f; v.w += 512.0f;
        *(float4*)&e2s[tid * 4] = v;
    }

    // ---- A fragments: 32 rows x 256 K per wave (one-time load) ----
    f16x8 a[2][8];
    #pragma unroll
    for (int mf = 0; mf < 2; ++mf) {
        const unsigned short* ap = xh + (((size_t)(rw + mf * 16 + l15)) << 8) + lg * 8;
        #pragma unroll
        for (int t = 0; t < 8; ++t)
            a[mf][t] = *(const f16x8*)(ap + t * 32);
    }
    __syncthreads();  // e2s visible

    // per-lane B base for this split (tiled layout): + tile*8192 + j*1024
    const char* bb = (const char*)ehT + (((size_t)c0s) << 9) + lane * 16;

    unsigned int p1[8], p2[8];
    #pragma unroll
    for (int r = 0; r < 8; ++r) { p1[r] = 0xFFFFFFFFu; p2[r] = 0xFFFFFFFFu; }

    f16x8 bA[8], bB[8];
    f32x4 accA[2], accB[2];

#define LOADT(breg, t)                                            \
    {                                                             \
        const char* tb_ = bb + (t) * 8192;                        \
        _Pragma("unroll")                                         \
        for (int j_ = 0; j_ < 8; ++j_)                            \
            breg[j_] = *(const f16x8*)(tb_ + j_ * 1024);          \
    }

#define MFMAT(acc, breg)                                          \
    {                                                             \
        _Pragma("unroll")                                         \
        for (int mf_ = 0; mf_ < 2; ++mf_) {                       \
            f32x4 z_ = {0.f, 0.f, 0.f, 0.f};                      \
            acc[mf_] = z_;                                        \
        }                                                         \
        _Pragma("unroll")                                         \
        for (int j_ = 0; j_ < 8; ++j_)                            \
            _Pragma("unroll")                                     \
            for (int mf_ = 0; mf_ < 2; ++mf_)                     \
                acc[mf_] = __builtin_amdgcn_mfma_f32_16x16x32_f16(\
                    a[mf_][j_], breg[j_], acc[mf_], 0, 0, 0);     \
    }

// biased-positive scores: raw bits are order-preserving; pack idx in low 10.
#define EPI(acc, tile)                                                        \
    {                                                                         \
        const float e2v_ = e2s[(tile) * 16 + l15];                            \
        const unsigned int cl_ = (unsigned int)((tile) * 16 + l15);           \
        _Pragma("unroll")                                                     \
        for (int mf_ = 0; mf_ < 2; ++mf_)                                     \
            _Pragma("unroll")                                                 \
            for (int rg_ = 0; rg_ < 4; ++rg_) {                               \
                const int rr_ = mf_ * 4 + rg_;                                \
                const float s_ = fmaf(-2.0f, acc[mf_][rg_], e2v_);            \
                const unsigned int sp_ =                                      \
                    (__float_as_uint(s_) & 0xFFFFFC00u) | cl_;                \
                const unsigned int hi_ = p1[rr_] > sp_ ? p1[rr_] : sp_;       \
                p1[rr_] = p1[rr_] < sp_ ? p1[rr_] : sp_;                      \
                p2[rr_] = p2[rr_] < hi_ ? p2[rr_] : hi_;                      \
            }                                                                 \
    }

    LOADT(bA, 0);
    #pragma unroll 1
    for (int t = 0; t < 64; t += 2) {
        __builtin_amdgcn_s_barrier();  // lockstep waves -> B streams alias in L1
        LOADT(bB, t + 1);          // t+1 <= 63 always
        MFMAT(accA, bA);
        if (t > 0) EPI(accB, t - 1);
        if (t + 2 < 64) LOADT(bA, t + 2);
        MFMAT(accB, bB);
        EPI(accA, t);
    }
    EPI(accB, 63);

    // butterfly top-2 merge across the 16-lane group (u32 packed)
    #pragma unroll
    for (int st = 1; st < 16; st <<= 1) {
        #pragma unroll
        for (int r = 0; r < 8; ++r) {
            const unsigned int q1 = (unsigned int)__shfl_xor((int)p1[r], st, 64);
            const unsigned int q2 = (unsigned int)__shfl_xor((int)p2[r], st, 64);
            const unsigned int n1 = p1[r] < q1 ? p1[r] : q1;
            const unsigned int hi = p1[r] < q1 ? q1 : p1[r];
            const unsigned int m2 = p2[r] < q2 ? p2[r] : q2;
            p1[r] = n1;
            p2[r] = m2 < hi ? m2 : hi;
        }
    }
    // waves own disjoint rows -> direct global write (code = c0s + idx10)
    if (l15 == 0) {
        #pragma unroll
        for (int mf = 0; mf < 2; ++mf)
            #pragma unroll
            for (int reg = 0; reg < 4; ++reg) {
                const int rr = mf * 4 + reg;
                const int n = rw + mf * 16 + lg * 4 + reg;
                unsigned int* cp = cand + (((size_t)n) << 4) + split * 2;
                cp[0] = (unsigned int)(c0s + (p1[rr] & 0x3FFu));
                cp[1] = (unsigned int)(c0s + (p2[rr] & 0x3FFu));
            }
    }
#undef LOADT
#undef MFMAT
#undef EPI
}

// exact f32 rescore of 16 candidates + gather + commit loss, fused.
// grid 1024 blocks x 256 threads; 16 tokens/block (4 iters x 4 waves).
__global__ void vq_rescore_finalize(const float* __restrict__ xt, const float* __restrict__ embed,
                                    const float* __restrict__ e2,
                                    const unsigned int* __restrict__ cand,
                                    float* __restrict__ out, double* __restrict__ dsum) {
    __shared__ double red[4];
    const int tid = threadIdx.x, wid = tid >> 6, lane = tid & 63;
    double wsum = 0.0;
    #pragma unroll 1
    for (int it = 0; it < 4; ++it) {
        const int n = blockIdx.x * 16 + it * 4 + wid;
        const float4 xv = *(const float4*)(xt + (((size_t)n) << 8) + lane * 4);
        unsigned long long best = 0xFFFFFFFFFFFFFFFFull;
        #pragma unroll 2
        for (int j = 0; j < 16; ++j) {
            const unsigned int c = cand[(((size_t)n) << 4) + j];
            const float4 ev = *(const float4*)(embed + (((size_t)c) << 8) + lane * 4);
            float dt = xv.x * ev.x + xv.y * ev.y + xv.z * ev.z + xv.w * ev.w;
            #pragma unroll
            for (int off = 32; off > 0; off >>= 1) dt += __shfl_xor(dt, off, 64);
            const float s = fmaf(-2.0f, dt, e2[c]);
            const unsigned long long p = (((unsigned long long)ford(s)) << 32) | c;
            best = p < best ? p : best;
        }
        const unsigned int bi = (unsigned int)(best & 0xFFFFFFFFull);
        if (lane == 0) out[IND_OFF + n] = (float)bi;
        const float4 ev = *(const float4*)(embed + (((size_t)bi) << 8) + lane * 4);
        *(float4*)(out + Q_OFF + (((size_t)n) << 8) + lane * 4) = ev;
        const float q0 = ev.x - xv.x, q1 = ev.y - xv.y, q2 = ev.z - xv.z, q3 = ev.w - xv.w;
        float a4 = q0 * q0 + q1 * q1 + q2 * q2 + q3 * q3;
        #pragma unroll
        for (int off = 32; off > 0; off >>= 1) a4 += __shfl_xor(a4, off, 64);
        if (lane == 0) wsum += (double)a4;
    }
    if (lane == 0) red[wid] = wsum;
    __syncthreads();
    if (tid == 0) atomicAdd(dsum, red[0] + red[1] + red[2] + red[3]);
}

__global__ void vq_tail_kernel(const float* __restrict__ cs,
                               const double* __restrict__ dsum,
                               float* __restrict__ out) {
    __shared__ double red[4];
    const int tid = threadIdx.x;
    double s = 0.0;
    for (int i = tid; i < K; i += 256) {
        const float p = cs[i];
        s += (double)(p * logf(p + 1e-5f));
    }
    #pragma unroll
    for (int off = 32; off > 0; off >>= 1) s += __shfl_down(s, off, 64);
    if ((tid & 63) == 0) red[tid >> 6] = s;
    __syncthreads();
    if (tid == 0) {
        const double tot = red[0] + red[1] + red[2] + red[3];
        const double pv = exp(-tot);
        out[PERP_OFF] = (pv > 3.3e38) ? 3.3e38f : (float)pv;
        out[COMMIT_OFF] = (float)(*dsum * (1.0 / 4194304.0));
    }
}

// ============================ FALLBACK (ws too small) ============================
#define TM 64
#define TN 64
#define BKF 32
#define NSPLITF 2
#define CODES_PER_SPLIT (K / NSPLITF)
#define TILES_PER_SPLIT (CODES_PER_SPLIT / TN)

__global__ void vq_init_kernel(unsigned long long* __restrict__ keys, double* __restrict__ dsum) {
    int i = blockIdx.x * blockDim.x + threadIdx.x;
    if (i < N_TOK) keys[i] = 0xFFFFFFFFFFFFFFFFull;
    if (i == 0) *dsum = 0.0;
}
__global__ void vq_e2_kernel(const float* __restrict__ embed, float* __restrict__ e2) {
    int wave = threadIdx.x >> 6, lane = threadIdx.x & 63;
    int c = blockIdx.x * 4 + wave;
    const float4 v = *(const float4*)(embed + (size_t)c * D + lane * 4);
    float s = v.x * v.x + v.y * v.y + v.z * v.z + v.w * v.w;
    #pragma unroll
    for (int off = 32; off > 0; off >>= 1) s += __shfl_down(s, off, 64);
    if (lane == 0) e2[c] = s;
}
__global__ __launch_bounds__(256, 2) void vq_argmin_kernel(
    const float* __restrict__ x, const float* __restrict__ embed,
    const float* __restrict__ e2, unsigned long long* __restrict__ keys) {
    __shared__ float xT[D][TM];
    __shared__ float eT[BKF][TN + 4];
    const int tid = threadIdx.x;
    const int n0 = blockIdx.x * TM;
    const int b = n0 >> 10, p0 = n0 & 1023;
    const float* xb = x + (size_t)b * D * 1024 + p0;
    {
        const int t4 = (tid & 15) * 4, chb = tid >> 4;
        #pragma unroll
        for (int pass = 0; pass < 16; ++pass) {
            const int ch = pass * 16 + chb;
            *(float4*)&xT[ch][t4] = *(const float4*)(xb + (size_t)ch * 1024 + t4);
        }
    }
    __syncthreads();
    const int tm4 = (tid & 15) * 4, tn = tid >> 4, tn4 = tn * 4;
    float bestd[4]; int besti[4];
    #pragma unroll
    for (int i = 0; i < 4; ++i) { bestd[i] = INFINITY; besti[i] = 0x7fffffff; }
    for (int ct = 0; ct < TILES_PER_SPLIT; ++ct) {
        const int c0 = blockIdx.y * CODES_PER_SPLIT + ct * TN;
        float acc[4][4] = {};
        for (int kk = 0; kk < D; kk += BKF) {
            {
                const int j = tid >> 2, ch4 = (tid & 3) * 4;
                #pragma unroll
                for (int p = 0; p < 2; ++p) {
                    const int chl = p * 16 + ch4;
                    const float4 ev = *(const float4*)(embed + (size_t)(c0 + j) * D + kk + chl);
                    eT[chl + 0][j] = ev.x; eT[chl + 1][j] = ev.y;
                    eT[chl + 2][j] = ev.z; eT[chl + 3][j] = ev.w;
                }
            }
            __syncthreads();
            #pragma unroll
            for (int k2 = 0; k2 < BKF; ++k2) {
                const float4 a = *(const float4*)&xT[kk + k2][tm4];
                const float4 bv = *(const float4*)&eT[k2][tn4];
                acc[0][0] += a.x * bv.x; acc[0][1] += a.x * bv.y; acc[0][2] += a.x * bv.z; acc[0][3] += a.x * bv.w;
                acc[1][0] += a.y * bv.x; acc[1][1] += a.y * bv.y; acc[1][2] += a.y * bv.z; acc[1][3] += a.y * bv.w;
                acc[2][0] += a.z * bv.x; acc[2][1] += a.z * bv.y; acc[2][2] += a.z * bv.z; acc[2][3] += a.z * bv.w;
                acc[3][0] += a.w * bv.x; acc[3][1] += a.w * bv.y; acc[3][2] += a.w * bv.z; acc[3][3] += a.w * bv.w;
            }
            __syncthreads();
        }
        #pragma unroll
        for (int j = 0; j < 4; ++j) {
            const int c = c0 + tn4 + j;
            const float ec = e2[c];
            #pragma unroll
            for (int i = 0; i < 4; ++i) {
                const float s = ec - 2.0f * acc[i][j];
                if (s < bestd[i]) { bestd[i] = s; besti[i] = c; }
            }
        }
    }
    __syncthreads();
    float* cd = &eT[0][0];
    int* ci = (int*)&eT[16][0];
    #pragma unroll
    for (int i = 0; i < 4; ++i) { cd[tn * 64 + tm4 + i] = bestd[i]; ci[tn * 64 + tm4 + i] = besti[i]; }
    __syncthreads();
    if (tid < TM) {
        float bd = INFINITY; int bi = 0x7fffffff;
        for (int j = 0; j < 16; ++j) {
            const float d = cd[j * 64 + tid]; const int idx = ci[j * 64 + tid];
            if (d < bd || (d == bd && idx < bi)) { bd = d; bi = idx; }
        }
        atomicMin(&keys[n0 + tid], (((unsigned long long)ford(bd)) << 32) | (unsigned int)bi);
    }
}
__global__ void vq_finalize_kernel(const float* __restrict__ x, const float* __restrict__ embed,
                                   const unsigned long long* __restrict__ keys,
                                   float* __restrict__ out, double* __restrict__ dsum) {
    const int tid = threadIdx.x;
    const int n0 = blockIdx.x * 64;
    const int t = tid >> 2, q = tid & 3;
    const int n = n0 + t;
    const int b = n >> 10, p = n & 1023;
    if (tid < 64) {
        const int nn = n0 + tid;
        out[IND_OFF + nn] = (float)(int)(unsigned int)(keys[nn] & 0xFFFFFFFFull);
    }
    const int idx = (int)(unsigned int)(keys[n] & 0xFFFFFFFFull);
    const float* erow = embed + (size_t)idx * D;
    const float* xrow = x + (size_t)b * D * 1024 + p;
    float* qrow = out + Q_OFF + (size_t)n * D;
    float acc = 0.0f;
    #pragma unroll
    for (int i = 0; i < 16; ++i) {
        const int ch = i * 16 + q * 4;
        const float4 ev = *(const float4*)(erow + ch);
        *(float4*)(qrow + ch) = ev;
        const float x0 = xrow[(size_t)(ch + 0) * 1024];
        const float x1 = xrow[(size_t)(ch + 1) * 1024];
        const float x2 = xrow[(size_t)(ch + 2) * 1024];
        const float x3 = xrow[(size_t)(ch + 3) * 1024];
        const float d0 = ev.x - x0, d1 = ev.y - x1, d2 = ev.z - x2, d3 = ev.w - x3;
        acc += d0 * d0 + d1 * d1 + d2 * d2 + d3 * d3;
    }
    #pragma unroll
    for (int off = 32; off > 0; off >>= 1) acc += __shfl_down(acc, off, 64);
    if ((tid & 63) == 0) atomicAdd(dsum, (double)acc);
}

extern "C" void kernel_launch(void* const* d_in, const int* in_sizes, int n_in,
                              void* d_out, int out_size, void* d_ws, size_t ws_size,
                              hipStream_t stream) {
    const float* x = (const float*)d_in[0];
    const float* embed = (const float*)d_in[1];
    const float* cs = (const float*)d_in[2];
    float* out = (float*)d_out;
    char* ws = (char*)d_ws;

    if (ws_size >= (size_t)WS_NEED) {
        unsigned int* cand = (unsigned int*)(ws + WS_CAND);
        float* e2 = (float*)(ws + WS_E2);
        double* dsum = (double*)(ws + WS_DSUM);
        unsigned short* ehT = (unsigned short*)(ws + WS_EH);
        unsigned short* xh = (unsigned short*)(ws + WS_XH);
        float* xt = (float*)(ws + WS_XT);

        vq_prep_e<<<dim3(K / 4), dim3(256), 0, stream>>>(embed, ehT, e2, dsum);
        vq_convert_x<<<dim3(16, 4, 16), dim3(256), 0, stream>>>(x, xt, xh);
        vq_mfma_kernel<<<dim3(128, 8), dim3(256), 0, stream>>>(xh, ehT, e2, cand);
        vq_rescore_finalize<<<dim3(1024), dim3(256), 0, stream>>>(xt, embed, e2, cand, out, dsum);
        vq_tail_kernel<<<dim3(1), dim3(256), 0, stream>>>(cs, dsum, out);
    } else {
        unsigned long long* keys = (unsigned long long*)ws;
        float* e2 = (float*)(ws + 131072);
        double* dsum = (double*)(ws + 163840);
        vq_init_kernel<<<dim3(64), dim3(256), 0, stream>>>(keys, dsum);
        vq_e2_kernel<<<dim3(K / 4), dim3(256), 0, stream>>>(embed, e2);
        vq_argmin_kernel<<<dim3(N_TOK / TM, NSPLITF), dim3(256), 0, stream>>>(x, embed, e2, keys);
        vq_finalize_kernel<<<dim3(256), dim3(256), 0, stream>>>(x, embed, keys, out, dsum);
        vq_tail_kernel<<<dim3(1), dim3(256), 0, stream>>>(cs, dsum, out);
    }
}

// Round 19
// 157.317 us; speedup vs baseline: 1.0852x; 1.0169x over previous
//
#include <hip/hip_runtime.h>
#include <hip/hip_bf16.h>
#include <math.h>

typedef _Float16 f16x8 __attribute__((ext_vector_type(8)));
typedef float f32x4 __attribute__((ext_vector_type(4)));

#define N_TOK 16384
#define D 256
#define K 8192

#define Q_OFF 0
#define IND_OFF 4194304
#define PERP_OFF 4210688
#define COMMIT_OFF 4210689

// ---------- ws layout (bytes) ----------
#define WS_CAND   0u          // u32[16384][16]  (1 MB)
#define WS_E2     1048576u    // f32[8192]
#define WS_DSUM   1081344u    // double
#define WS_EH     1114112u    // f16 tiled ehT[512 tiles][32 chunks][16 rows][8] (4 MB)
#define WS_XH     5308416u    // f16[16384][256] (8 MB)
#define WS_XT     13697024u   // f32[16384][256] (16 MB)
#define WS_NEED   30474240u

__device__ __forceinline__ unsigned int ford(float f) {
    unsigned int u = __float_as_uint(f);
    return (u & 0x80000000u) ? ~u : (u | 0x80000000u);
}
__device__ __forceinline__ unsigned short f2h(float f) {
    _Float16 h = (_Float16)f;
    return *(unsigned short*)&h;
}

// ============================ FAST PATH ============================

// transpose x: (b,c,p) f32 -> XT[n][c] f32 and Xh[n][c] f16 (row-major)
__global__ void vq_convert_x(const float* __restrict__ x, float* __restrict__ xt,
                             unsigned short* __restrict__ xh) {
    __shared__ float t[64][65];
    const int tid = threadIdx.x;
    const int p0 = blockIdx.x * 64, c0 = blockIdx.y * 64, b = blockIdx.z;
    const int q = tid & 15, h = tid >> 4;
    #pragma unroll
    for (int r = 0; r < 4; ++r) {
        const int cl = r * 16 + h;
        const float4 v = *(const float4*)(x + (((size_t)(b * 256 + c0 + cl)) << 10) + p0 + q * 4);
        t[cl][q * 4 + 0] = v.x; t[cl][q * 4 + 1] = v.y;
        t[cl][q * 4 + 2] = v.z; t[cl][q * 4 + 3] = v.w;
    }
    __syncthreads();
    #pragma unroll
    for (int r = 0; r < 4; ++r) {
        const int nl = r * 16 + h;
        const int n = (b << 10) + p0 + nl;
        const int c = c0 + q * 4;
        float4 vf; ushort4 vh;
        vf.x = t[q * 4 + 0][nl]; vf.y = t[q * 4 + 1][nl];
        vf.z = t[q * 4 + 2][nl]; vf.w = t[q * 4 + 3][nl];
        vh.x = f2h(vf.x); vh.y = f2h(vf.y); vh.z = f2h(vf.z); vh.w = f2h(vf.w);
        *(float4*)(xt + ((size_t)n << 8) + c) = vf;
        *(ushort4*)(xh + ((size_t)n << 8) + c) = vh;
    }
}

// fused: embed -> f16 in MFMA-fragment tiled order, e2 row norms, dsum init.
// ehT element index = (c>>4)*4096 + (k>>3)*128 + (c&15)*8 + (k&7).
__global__ void vq_prep_e(const float* __restrict__ e, unsigned short* __restrict__ ehT,
                          float* __restrict__ e2, double* __restrict__ dsum) {
    if (blockIdx.x == 0 && threadIdx.x == 0) *dsum = 0.0;
    const int wave = threadIdx.x >> 6, lane = threadIdx.x & 63;
    const int c = blockIdx.x * 4 + wave;
    const float4 v = *(const float4*)(e + (size_t)c * D + lane * 4);
    ushort4 vh;
    vh.x = f2h(v.x); vh.y = f2h(v.y); vh.z = f2h(v.z); vh.w = f2h(v.w);
    unsigned short* dst = ehT + (((size_t)(c >> 4)) << 12) + ((lane >> 1) << 7) +
                          ((c & 15) << 3) + ((lane & 1) << 2);
    *(ushort4*)dst = vh;
    float s = v.x * v.x + v.y * v.y + v.z * v.z + v.w * v.w;
    #pragma unroll
    for (int off = 32; off > 0; off >>= 1) s += __shfl_down(s, off, 64);
    if (lane == 0) e2[c] = s;
}

// fp16 screen GEMM + per-split top-2 -- zero LDS staging, zero barriers,
// software-pipelined (b(t+1) loads before MFMA(t), EPI(t-1) in MFMA shadow),
// 32 rows/wave, ~3 waves/SIMD TLP. Best-measured config (r16: 95.7us).
// grid (128 M-tiles, 8 splits) = 1024 blocks of 256 threads (4 waves x 32 rows).
__global__ __launch_bounds__(256)
void vq_mfma_kernel(
    const unsigned short* __restrict__ xh, const unsigned short* __restrict__ ehT,
    const float* __restrict__ e2, unsigned int* __restrict__ cand) {
    __shared__ float e2s[1024];  // 4 KB, pre-biased +512

    const int tid = threadIdx.x;
    const int lane = tid & 63, wid = tid >> 6;   // 4 waves
    const int l15 = lane & 15, lg = lane >> 4;
    const int split = blockIdx.y;
    const int m0 = blockIdx.x * 128;
    const int c0s = split * 1024;
    const int rw = m0 + wid * 32;  // wave's first token row (32 rows/wave)

    {
        float4 v = *(const float4*)(e2 + c0s + tid * 4);
        v.x += 512.0f; v.y += 512.0f; v.z += 512.0f; v.w += 512.0f;
        *(float4*)&e2s[tid * 4] = v;
    }

    // ---- A fragments: 32 rows x 256 K per wave (one-time load) ----
    f16x8 a[2][8];
    #pragma unroll
    for (int mf = 0; mf < 2; ++mf) {
        const unsigned short* ap = xh + (((size_t)(rw + mf * 16 + l15)) << 8) + lg * 8;
        #pragma unroll
        for (int t = 0; t < 8; ++t)
            a[mf][t] = *(const f16x8*)(ap + t * 32);
    }
    __syncthreads();  // e2s visible

    // per-lane B base for this split (tiled layout): + tile*8192 + j*1024
    const char* bb = (const char*)ehT + (((size_t)c0s) << 9) + lane * 16;

    unsigned int p1[8], p2[8];
    #pragma unroll
    for (int r = 0; r < 8; ++r) { p1[r] = 0xFFFFFFFFu; p2[r] = 0xFFFFFFFFu; }

    f16x8 bA[8], bB[8];
    f32x4 accA[2], accB[2];

#define LOADT(breg, t)                                            \
    {                                                             \
        const char* tb_ = bb + (t) * 8192;                        \
        _Pragma("unroll")                                         \
        for (int j_ = 0; j_ < 8; ++j_)                            \
            breg[j_] = *(const f16x8*)(tb_ + j_ * 1024);          \
    }

#define MFMAT(acc, breg)                                          \
    {                                                             \
        _Pragma("unroll")                                         \
        for (int mf_ = 0; mf_ < 2; ++mf_) {                       \
            f32x4 z_ = {0.f, 0.f, 0.f, 0.f};                      \
            acc[mf_] = z_;                                        \
        }                                                         \
        _Pragma("unroll")                                         \
        for (int j_ = 0; j_ < 8; ++j_)                            \
            _Pragma("unroll")                                     \
            for (int mf_ = 0; mf_ < 2; ++mf_)                     \
                acc[mf_] = __builtin_amdgcn_mfma_f32_16x16x32_f16(\
                    a[mf_][j_], breg[j_], acc[mf_], 0, 0, 0);     \
    }

// biased-positive scores: raw bits are order-preserving; pack idx in low 10.
#define EPI(acc, tile)                                                        \
    {                                                                         \
        const float e2v_ = e2s[(tile) * 16 + l15];                            \
        const unsigned int cl_ = (unsigned int)((tile) * 16 + l15);           \
        _Pragma("unroll")                                                     \
        for (int mf_ = 0; mf_ < 2; ++mf_)                                     \
            _Pragma("unroll")                                                 \
            for (int rg_ = 0; rg_ < 4; ++rg_) {                               \
                const int rr_ = mf_ * 4 + rg_;                                \
                const float s_ = fmaf(-2.0f, acc[mf_][rg_], e2v_);            \
                const unsigned int sp_ =                                      \
                    (__float_as_uint(s_) & 0xFFFFFC00u) | cl_;                \
                const unsigned int hi_ = p1[rr_] > sp_ ? p1[rr_] : sp_;       \
                p1[rr_] = p1[rr_] < sp_ ? p1[rr_] : sp_;                      \
                p2[rr_] = p2[rr_] < hi_ ? p2[rr_] : hi_;                      \
            }                                                                 \
    }

    LOADT(bA, 0);
    #pragma unroll 1
    for (int t = 0; t < 64; t += 2) {
        LOADT(bB, t + 1);          // t+1 <= 63 always
        MFMAT(accA, bA);
        if (t > 0) EPI(accB, t - 1);
        if (t + 2 < 64) LOADT(bA, t + 2);
        MFMAT(accB, bB);
        EPI(accA, t);
    }
    EPI(accB, 63);

    // butterfly top-2 merge across the 16-lane group (u32 packed)
    #pragma unroll
    for (int st = 1; st < 16; st <<= 1) {
        #pragma unroll
        for (int r = 0; r < 8; ++r) {
            const unsigned int q1 = (unsigned int)__shfl_xor((int)p1[r], st, 64);
            const unsigned int q2 = (unsigned int)__shfl_xor((int)p2[r], st, 64);
            const unsigned int n1 = p1[r] < q1 ? p1[r] : q1;
            const unsigned int hi = p1[r] < q1 ? q1 : p1[r];
            const unsigned int m2 = p2[r] < q2 ? p2[r] : q2;
            p1[r] = n1;
            p2[r] = m2 < hi ? m2 : hi;
        }
    }
    // waves own disjoint rows -> direct global write (code = c0s + idx10)
    if (l15 == 0) {
        #pragma unroll
        for (int mf = 0; mf < 2; ++mf)
            #pragma unroll
            for (int reg = 0; reg < 4; ++reg) {
                const int rr = mf * 4 + reg;
                const int n = rw + mf * 16 + lg * 4 + reg;
                unsigned int* cp = cand + (((size_t)n) << 4) + split * 2;
                cp[0] = (unsigned int)(c0s + (p1[rr] & 0x3FFu));
                cp[1] = (unsigned int)(c0s + (p2[rr] & 0x3FFu));
            }
    }
#undef LOADT
#undef MFMAT
#undef EPI
}

// exact f32 rescore of 16 candidates + gather + commit loss, fused.
// grid 1024 blocks x 256 threads; 16 tokens/block (4 iters x 4 waves).
__global__ void vq_rescore_finalize(const float* __restrict__ xt, const float* __restrict__ embed,
                                    const float* __restrict__ e2,
                                    const unsigned int* __restrict__ cand,
                                    float* __restrict__ out, double* __restrict__ dsum) {
    __shared__ double red[4];
    const int tid = threadIdx.x, wid = tid >> 6, lane = tid & 63;
    double wsum = 0.0;
    #pragma unroll 1
    for (int it = 0; it < 4; ++it) {
        const int n = blockIdx.x * 16 + it * 4 + wid;
        const float4 xv = *(const float4*)(xt + (((size_t)n) << 8) + lane * 4);
        unsigned long long best = 0xFFFFFFFFFFFFFFFFull;
        #pragma unroll 2
        for (int j = 0; j < 16; ++j) {
            const unsigned int c = cand[(((size_t)n) << 4) + j];
            const float4 ev = *(const float4*)(embed + (((size_t)c) << 8) + lane * 4);
            float dt = xv.x * ev.x + xv.y * ev.y + xv.z * ev.z + xv.w * ev.w;
            #pragma unroll
            for (int off = 32; off > 0; off >>= 1) dt += __shfl_xor(dt, off, 64);
            const float s = fmaf(-2.0f, dt, e2[c]);
            const unsigned long long p = (((unsigned long long)ford(s)) << 32) | c;
            best = p < best ? p : best;
        }
        const unsigned int bi = (unsigned int)(best & 0xFFFFFFFFull);
        if (lane == 0) out[IND_OFF + n] = (float)bi;
        const float4 ev = *(const float4*)(embed + (((size_t)bi) << 8) + lane * 4);
        *(float4*)(out + Q_OFF + (((size_t)n) << 8) + lane * 4) = ev;
        const float q0 = ev.x - xv.x, q1 = ev.y - xv.y, q2 = ev.z - xv.z, q3 = ev.w - xv.w;
        float a4 = q0 * q0 + q1 * q1 + q2 * q2 + q3 * q3;
        #pragma unroll
        for (int off = 32; off > 0; off >>= 1) a4 += __shfl_xor(a4, off, 64);
        if (lane == 0) wsum += (double)a4;
    }
    if (lane == 0) red[wid] = wsum;
    __syncthreads();
    if (tid == 0) atomicAdd(dsum, red[0] + red[1] + red[2] + red[3]);
}

__global__ void vq_tail_kernel(const float* __restrict__ cs,
                               const double* __restrict__ dsum,
                               float* __restrict__ out) {
    __shared__ double red[4];
    const int tid = threadIdx.x;
    double s = 0.0;
    for (int i = tid; i < K; i += 256) {
        const float p = cs[i];
        s += (double)(p * logf(p + 1e-5f));
    }
    #pragma unroll
    for (int off = 32; off > 0; off >>= 1) s += __shfl_down(s, off, 64);
    if ((tid & 63) == 0) red[tid >> 6] = s;
    __syncthreads();
    if (tid == 0) {
        const double tot = red[0] + red[1] + red[2] + red[3];
        const double pv = exp(-tot);
        out[PERP_OFF] = (pv > 3.3e38) ? 3.3e38f : (float)pv;
        out[COMMIT_OFF] = (float)(*dsum * (1.0 / 4194304.0));
    }
}

// ============================ FALLBACK (ws too small) ============================
#define TM 64
#define TN 64
#define BKF 32
#define NSPLITF 2
#define CODES_PER_SPLIT (K / NSPLITF)
#define TILES_PER_SPLIT (CODES_PER_SPLIT / TN)

__global__ void vq_init_kernel(unsigned long long* __restrict__ keys, double* __restrict__ dsum) {
    int i = blockIdx.x * blockDim.x + threadIdx.x;
    if (i < N_TOK) keys[i] = 0xFFFFFFFFFFFFFFFFull;
    if (i == 0) *dsum = 0.0;
}
__global__ void vq_e2_kernel(const float* __restrict__ embed, float* __restrict__ e2) {
    int wave = threadIdx.x >> 6, lane = threadIdx.x & 63;
    int c = blockIdx.x * 4 + wave;
    const float4 v = *(const float4*)(embed + (size_t)c * D + lane * 4);
    float s = v.x * v.x + v.y * v.y + v.z * v.z + v.w * v.w;
    #pragma unroll
    for (int off = 32; off > 0; off >>= 1) s += __shfl_down(s, off, 64);
    if (lane == 0) e2[c] = s;
}
__global__ __launch_bounds__(256, 2) void vq_argmin_kernel(
    const float* __restrict__ x, const float* __restrict__ embed,
    const float* __restrict__ e2, unsigned long long* __restrict__ keys) {
    __shared__ float xT[D][TM];
    __shared__ float eT[BKF][TN + 4];
    const int tid = threadIdx.x;
    const int n0 = blockIdx.x * TM;
    const int b = n0 >> 10, p0 = n0 & 1023;
    const float* xb = x + (size_t)b * D * 1024 + p0;
    {
        const int t4 = (tid & 15) * 4, chb = tid >> 4;
        #pragma unroll
        for (int pass = 0; pass < 16; ++pass) {
            const int ch = pass * 16 + chb;
            *(float4*)&xT[ch][t4] = *(const float4*)(xb + (size_t)ch * 1024 + t4);
        }
    }
    __syncthreads();
    const int tm4 = (tid & 15) * 4, tn = tid >> 4, tn4 = tn * 4;
    float bestd[4]; int besti[4];
    #pragma unroll
    for (int i = 0; i < 4; ++i) { bestd[i] = INFINITY; besti[i] = 0x7fffffff; }
    for (int ct = 0; ct < TILES_PER_SPLIT; ++ct) {
        const int c0 = blockIdx.y * CODES_PER_SPLIT + ct * TN;
        float acc[4][4] = {};
        for (int kk = 0; kk < D; kk += BKF) {
            {
                const int j = tid >> 2, ch4 = (tid & 3) * 4;
                #pragma unroll
                for (int p = 0; p < 2; ++p) {
                    const int chl = p * 16 + ch4;
                    const float4 ev = *(const float4*)(embed + (size_t)(c0 + j) * D + kk + chl);
                    eT[chl + 0][j] = ev.x; eT[chl + 1][j] = ev.y;
                    eT[chl + 2][j] = ev.z; eT[chl + 3][j] = ev.w;
                }
            }
            __syncthreads();
            #pragma unroll
            for (int k2 = 0; k2 < BKF; ++k2) {
                const float4 a = *(const float4*)&xT[kk + k2][tm4];
                const float4 bv = *(const float4*)&eT[k2][tn4];
                acc[0][0] += a.x * bv.x; acc[0][1] += a.x * bv.y; acc[0][2] += a.x * bv.z; acc[0][3] += a.x * bv.w;
                acc[1][0] += a.y * bv.x; acc[1][1] += a.y * bv.y; acc[1][2] += a.y * bv.z; acc[1][3] += a.y * bv.w;
                acc[2][0] += a.z * bv.x; acc[2][1] += a.z * bv.y; acc[2][2] += a.z * bv.z; acc[2][3] += a.z * bv.w;
                acc[3][0] += a.w * bv.x; acc[3][1] += a.w * bv.y; acc[3][2] += a.w * bv.z; acc[3][3] += a.w * bv.w;
            }
            __syncthreads();
        }
        #pragma unroll
        for (int j = 0; j < 4; ++j) {
            const int c = c0 + tn4 + j;
            const float ec = e2[c];
            #pragma unroll
            for (int i = 0; i < 4; ++i) {
                const float s = ec - 2.0f * acc[i][j];
                if (s < bestd[i]) { bestd[i] = s; besti[i] = c; }
            }
        }
    }
    __syncthreads();
    float* cd = &eT[0][0];
    int* ci = (int*)&eT[16][0];
    #pragma unroll
    for (int i = 0; i < 4; ++i) { cd[tn * 64 + tm4 + i] = bestd[i]; ci[tn * 64 + tm4 + i] = besti[i]; }
    __syncthreads();
    if (tid < TM) {
        float bd = INFINITY; int bi = 0x7fffffff;
        for (int j = 0; j < 16; ++j) {
            const float d = cd[j * 64 + tid]; const int idx = ci[j * 64 + tid];
            if (d < bd || (d == bd && idx < bi)) { bd = d; bi = idx; }
        }
        atomicMin(&keys[n0 + tid], (((unsigned long long)ford(bd)) << 32) | (unsigned int)bi);
    }
}
__global__ void vq_finalize_kernel(const float* __restrict__ x, const float* __restrict__ embed,
                                   const unsigned long long* __restrict__ keys,
                                   float* __restrict__ out, double* __restrict__ dsum) {
    const int tid = threadIdx.x;
    const int n0 = blockIdx.x * 64;
    const int t = tid >> 2, q = tid & 3;
    const int n = n0 + t;
    const int b = n >> 10, p = n & 1023;
    if (tid < 64) {
        const int nn = n0 + tid;
        out[IND_OFF + nn] = (float)(int)(unsigned int)(keys[nn] & 0xFFFFFFFFull);
    }
    const int idx = (int)(unsigned int)(keys[n] & 0xFFFFFFFFull);
    const float* erow = embed + (size_t)idx * D;
    const float* xrow = x + (size_t)b * D * 1024 + p;
    float* qrow = out + Q_OFF + (size_t)n * D;
    float acc = 0.0f;
    #pragma unroll
    for (int i = 0; i < 16; ++i) {
        const int ch = i * 16 + q * 4;
        const float4 ev = *(const float4*)(erow + ch);
        *(float4*)(qrow + ch) = ev;
        const float x0 = xrow[(size_t)(ch + 0) * 1024];
        const float x1 = xrow[(size_t)(ch + 1) * 1024];
        const float x2 = xrow[(size_t)(ch + 2) * 1024];
        const float x3 = xrow[(size_t)(ch + 3) * 1024];
        const float d0 = ev.x - x0, d1 = ev.y - x1, d2 = ev.z - x2, d3 = ev.w - x3;
        acc += d0 * d0 + d1 * d1 + d2 * d2 + d3 * d3;
    }
    #pragma unroll
    for (int off = 32; off > 0; off >>= 1) acc += __shfl_down(acc, off, 64);
    if ((tid & 63) == 0) atomicAdd(dsum, (double)acc);
}

extern "C" void kernel_launch(void* const* d_in, const int* in_sizes, int n_in,
                              void* d_out, int out_size, void* d_ws, size_t ws_size,
                              hipStream_t stream) {
    const float* x = (const float*)d_in[0];
    const float* embed = (const float*)d_in[1];
    const float* cs = (const float*)d_in[2];
    float* out = (float*)d_out;
    char* ws = (char*)d_ws;

    if (ws_size >= (size_t)WS_NEED) {
        unsigned int* cand = (unsigned int*)(ws + WS_CAND);
        float* e2 = (float*)(ws + WS_E2);
        double* dsum = (double*)(ws + WS_DSUM);
        unsigned short* ehT = (unsigned short*)(ws + WS_EH);
        unsigned short* xh = (unsigned short*)(ws + WS_XH);
        float* xt = (float*)(ws + WS_XT);

        vq_prep_e<<<dim3(K / 4), dim3(256), 0, stream>>>(embed, ehT, e2, dsum);
        vq_convert_x<<<dim3(16, 4, 16), dim3(256), 0, stream>>>(x, xt, xh);
        vq_mfma_kernel<<<dim3(128, 8), dim3(256), 0, stream>>>(xh, ehT, e2, cand);
        vq_rescore_finalize<<<dim3(1024), dim3(256), 0, stream>>>(xt, embed, e2, cand, out, dsum);
        vq_tail_kernel<<<dim3(1), dim3(256), 0, stream>>>(cs, dsum, out);
    } else {
        unsigned long long* keys = (unsigned long long*)ws;
        float* e2 = (float*)(ws + 131072);
        double* dsum = (double*)(ws + 163840);
        vq_init_kernel<<<dim3(64), dim3(256), 0, stream>>>(keys, dsum);
        vq_e2_kernel<<<dim3(K / 4), dim3(256), 0, stream>>>(embed, e2);
        vq_argmin_kernel<<<dim3(N_TOK / TM, NSPLITF), dim3(256), 0, stream>>>(x, embed, e2, keys);
        vq_finalize_kernel<<<dim3(256), dim3(256), 0, stream>>>(x, embed, keys, out, dsum);
        vq_tail_kernel<<<dim3(1), dim3(256), 0, stream>>>(cs, dsum, out);
    }
}